// Round 5
// baseline (197.687 us; speedup 1.0000x reference)
//
#include <hip/hip_runtime.h>
#include <stdint.h>

constexpr int K      = 49;           // 7x7 kernel flattened
constexpr int C      = 32;           // out channels
constexpr int TILE   = 64;           // windows per tile
constexpr int TILE_F = TILE * K;     // 3136 floats = 12544 B
constexpr int RING   = 3;            // LDS ring slots -> 37632 B/block
constexpr int BLK    = 256;          // 4 waves/block
constexpr int GRID   = 1024;         // 4 blocks/CU x 256 CU, co-resident
constexpr int NT     = 16;           // tiles per block (16384/1024), compile-time
constexpr int CPW    = C / 4;        // 8 channels per wave

#define GPTR(p) ((const __attribute__((address_space(1))) uint32_t*)(p))
#define LPTR(p) ((__attribute__((address_space(3))) uint32_t*)(p))
#define WAITV(n) asm volatile("s_waitcnt vmcnt(" #n ")" ::: "memory")

// Wave w issues its share of one 12544B tile stage: waves 0..2 -> 3 x 16B rounds,
// wave 3 -> 3 x 16B rounds + 1 x 4B tail. Lw = 3,3,3,4 VMEM ops (per-wave constant).
__device__ __forceinline__ void stage_share(const float* __restrict__ g,
                                            float* slot, int wid, int lane) {
    if (wid < 3) {
#pragma unroll
        for (int r = 0; r < 3; ++r) {
            const int rr = wid * 3 + r;
            __builtin_amdgcn_global_load_lds(GPTR(g + rr * 256 + lane * 4),
                                             LPTR(slot + rr * 256 + lane * 4), 16, 0, 0);
        }
    } else {
#pragma unroll
        for (int rr = 9; rr < 12; ++rr)
            __builtin_amdgcn_global_load_lds(GPTR(g + rr * 256 + lane * 4),
                                             LPTR(slot + rr * 256 + lane * 4), 16, 0, 0);
        __builtin_amdgcn_global_load_lds(GPTR(g + 3072 + lane),
                                         LPTR(slot + 3072 + lane), 4, 0, 0);
    }
}

// Per-wave VMEM FIFO (P=stage share Lw, S=stores 8), body order:
//   [wait P_j][s_barrier][ds_read x][P_{j+2}][compute][S_j]
// Younger-than-P_j at wait_j: S_{j-2}? NO - S_{j-2} is OLDER (issued after... )
//   issue order: P0 P1 | P2 S0 | P3 S1 | ... | P_{j+2} S_j | ...
//   younger than P_j (issued in iter j-2): S_{j-2}, P_{j+1}, S_{j-1} = 16+Lw.
// Stores are always YOUNGER than the load being waited -> never chained.
__global__ __launch_bounds__(BLK, 4) void conv2d_ring(
    const float* __restrict__ enc_x,
    const float* __restrict__ weight,   // [C*K]; c-outer/k-unrolled -> s_load_dwordx16
    const float* __restrict__ bias,     // [C]
    float* __restrict__ out,            // [C * windows_nb]
    int windows_nb)
{
    __shared__ __align__(16) float ring[RING][TILE_F];   // 37632 B

    const int t    = threadIdx.x;
    const int lane = t & 63;
    const int wid  = t >> 6;                 // wave id -> channel group
    const int b    = blockIdx.x;

    const float* __restrict__ gbase = enc_x + (size_t)b * NT * TILE_F;  // contiguous 784KB/block

    // Prologue: stage tiles 0 and 1.
    stage_share(gbase + 0 * TILE_F, ring[0], wid, lane);
    stage_share(gbase + 1 * TILE_F, ring[1], wid, lane);

    const float* __restrict__ wp = weight + wid * CPW * K;   // uniform per wave
    float bia[CPW];
#pragma unroll
    for (int cc = 0; cc < CPW; ++cc) bia[cc] = bias[wid * CPW + cc];

#pragma unroll
    for (int j = 0; j < NT; ++j) {
        // Counted wait for tile j's loads (stores stay younger, never waited).
        if (wid < 3) {
            if      (j == 0)      WAITV(3);
            else if (j == 1)      WAITV(11);
            else if (j < NT - 1)  WAITV(19);
            else                  WAITV(16);
        } else {
            if      (j == 0)      WAITV(4);
            else if (j == 1)      WAITV(12);
            else if (j < NT - 1)  WAITV(20);
            else                  WAITV(16);
        }
        __builtin_amdgcn_s_barrier();        // whole tile j resident (all waves waited)

        const float* __restrict__ xs = ring[j % RING];   // compile-time (unrolled)

        // Lane's window row -> registers. Bank = (lane*49+k)%32, lane*17%32 -> 2 lanes/bank, free.
        float x[K];
#pragma unroll
        for (int k = 0; k < K; ++k) x[k] = xs[lane * K + k];

        // Prefetch tile j+2 into the slot holding tile j-1 (all waves are past
        // barrier_j, so every wave finished reading tile j-1 in iter j-1).
        if (j + 2 < NT)
            stage_share(gbase + (size_t)(j + 2) * TILE_F, ring[(j + 2) % RING], wid, lane);

        const size_t w = (size_t)(b * NT + j) * TILE + lane;

        // 8 channels, c-outer, k fully unrolled -> 49 consecutive weights/channel
        // -> wide s_loads; unroll 2 pipelines next channel's s_loads under FMAs.
#pragma unroll 2
        for (int cc = 0; cc < CPW; ++cc) {
            const float* __restrict__ wc = wp + cc * K;
            float a0 = bia[cc], a1 = 0.f, a2 = 0.f, a3 = 0.f;
#pragma unroll
            for (int k = 0; k < K; k += 4) {
                a0 = fmaf(x[k], wc[k], a0);
                if (k + 1 < K) a1 = fmaf(x[k + 1], wc[k + 1], a1);
                if (k + 2 < K) a2 = fmaf(x[k + 2], wc[k + 2], a2);
                if (k + 3 < K) a3 = fmaf(x[k + 3], wc[k + 3], a3);
            }
            // nt store: no L2/L3 allocate -> keep enc_x cached instead of output
            __builtin_nontemporal_store((a0 + a1) + (a2 + a3),
                                        &out[(size_t)(wid * CPW + cc) * windows_nb + w]);
        }
    }
}

// Fallback (known-good round-4 kernel) for unexpected sizes.
__global__ __launch_bounds__(TILE) void conv2d_tile64(
    const float* __restrict__ enc_x, const float* __restrict__ weight,
    const float* __restrict__ bias, float* __restrict__ out, int windows_nb)
{
    __shared__ __align__(16) float xs[TILE_F];
    const int lane = threadIdx.x;
    const size_t b = blockIdx.x;
    const float* __restrict__ g = enc_x + b * TILE_F;
#pragma unroll
    for (int r = 0; r < 12; ++r)
        __builtin_amdgcn_global_load_lds(GPTR(g + r * 256 + lane * 4),
                                         LPTR(xs + r * 256 + lane * 4), 16, 0, 0);
    __builtin_amdgcn_global_load_lds(GPTR(g + 3072 + lane), LPTR(xs + 3072 + lane), 4, 0, 0);
    asm volatile("s_waitcnt vmcnt(0)" ::: "memory");
    float x[K];
#pragma unroll
    for (int k = 0; k < K; ++k) x[k] = xs[lane * K + k];
    const size_t w = b * TILE + lane;
#pragma unroll 2
    for (int c = 0; c < C; ++c) {
        const float* __restrict__ wc = weight + c * K;
        float a0 = bias[c], a1 = 0.f, a2 = 0.f, a3 = 0.f;
#pragma unroll
        for (int k = 0; k < K; k += 4) {
            a0 = fmaf(x[k], wc[k], a0);
            if (k + 1 < K) a1 = fmaf(x[k + 1], wc[k + 1], a1);
            if (k + 2 < K) a2 = fmaf(x[k + 2], wc[k + 2], a2);
            if (k + 3 < K) a3 = fmaf(x[k + 3], wc[k + 3], a3);
        }
        out[(size_t)c * windows_nb + w] = (a0 + a1) + (a2 + a3);
    }
}

extern "C" void kernel_launch(void* const* d_in, const int* in_sizes, int n_in,
                              void* d_out, int out_size, void* d_ws, size_t ws_size,
                              hipStream_t stream) {
    const float* enc_x  = (const float*)d_in[0];
    const float* weight = (const float*)d_in[1];
    const float* bias   = (const float*)d_in[2];
    float* out = (float*)d_out;

    const int windows_nb = in_sizes[0] / K;            // 1048576 expected

    if (windows_nb == GRID * NT * TILE) {
        conv2d_ring<<<GRID, BLK, 0, stream>>>(enc_x, weight, bias, out, windows_nb);
    } else {
        conv2d_tile64<<<windows_nb / TILE, TILE, 0, stream>>>(enc_x, weight, bias, out, windows_nb);
    }
}

// Round 6
// 84.353 us; speedup vs baseline: 2.3436x; 2.3436x over previous
//
#include <hip/hip_runtime.h>

constexpr int K   = 49;    // 7x7 kernel flattened
constexpr int C   = 32;    // out channels
constexpr int BLK = 256;   // 4 waves/block, blocks fully independent

// 4-byte-aligned float4: row base (w*196 B) is only dword-aligned.
// gfx950 supports unaligned global loads in HW -> still global_load_dwordx4.
typedef float v4 __attribute__((ext_vector_type(4), aligned(4)));

__global__ __launch_bounds__(BLK) void conv2d_direct(
    const float* __restrict__ enc_x,
    const float* __restrict__ weight,   // [C*K]; c-outer/k-unrolled -> wide s_loads
    const float* __restrict__ bias,     // [C]
    float* __restrict__ out,            // [C * windows_nb]
    int windows_nb)
{
    const size_t w = (size_t)blockIdx.x * BLK + threadIdx.x;
    const float* __restrict__ row = enc_x + w * (size_t)K;

    // Direct global->register: 12 x dwordx4 + 1 x dword, no LDS, no barriers.
    // Wave's 13 loads collectively cover a dense 12.5 KB span -> 100% line use via L1.
    float x[K];
#pragma unroll
    for (int r = 0; r < 12; ++r) {
        v4 v = *reinterpret_cast<const v4*>(row + r * 4);
#pragma unroll
        for (int i = 0; i < 4; ++i) x[r * 4 + i] = v[i];
    }
    x[48] = row[48];    // avoid 12 B overread past buffer end on last window

    // c outer, k fully unrolled: 49 consecutive weights/channel -> s_load_dwordx16;
    // unroll 2 lets channel c+1's s_loads pipeline under channel c's FMAs.
    // Compiler interleaves progressive vmcnt waits with early channels' FMAs.
#pragma unroll 2
    for (int c = 0; c < C; ++c) {
        const float* __restrict__ wc = weight + c * K;
        float a0 = bias[c], a1 = 0.f, a2 = 0.f, a3 = 0.f;
#pragma unroll
        for (int k = 0; k < K; k += 4) {
            a0 = fmaf(x[k], wc[k], a0);
            if (k + 1 < K) a1 = fmaf(x[k + 1], wc[k + 1], a1);
            if (k + 2 < K) a2 = fmaf(x[k + 2], wc[k + 2], a2);
            if (k + 3 < K) a3 = fmaf(x[k + 3], wc[k + 3], a3);
        }
        out[(size_t)c * windows_nb + w] = (a0 + a1) + (a2 + a3);
    }
}

extern "C" void kernel_launch(void* const* d_in, const int* in_sizes, int n_in,
                              void* d_out, int out_size, void* d_ws, size_t ws_size,
                              hipStream_t stream) {
    const float* enc_x  = (const float*)d_in[0];
    const float* weight = (const float*)d_in[1];   // [C,7,7] flat
    const float* bias   = (const float*)d_in[2];   // [C]
    float* out = (float*)d_out;

    const int windows_nb = in_sizes[0] / K;        // 1048576
    const int nblocks = (windows_nb + BLK - 1) / BLK;   // 4096

    conv2d_direct<<<nblocks, BLK, 0, stream>>>(enc_x, weight, bias, out, windows_nb);
}